// Round 4
// baseline (112.052 us; speedup 1.0000x reference)
//
#include <hip/hip_runtime.h>

// Problem constants (from reference)
#define B_SZ   256
#define L_SZ   200
#define EMBED  128
#define MAX_G  8
#define NTOK   (B_SZ * L_SZ)        // 51200 tokens
#define HALF   (NTOK / 2)           // 25600
#define F4_PER_ROW (EMBED / 4)      // 32 float4 per embedding row

typedef float nativef4 __attribute__((ext_vector_type(4)));  // for nontemporal store

// 32 lanes per token-slot, each lane owns one float4 of the 128-float row.
// Each thread processes TWO tokens (idx and idx+HALF) as independent chains
// to double memory-level parallelism (latency-bound gather).
// Block = 256 threads = 8 slots; grid = HALF/8 = 3200 blocks.
__global__ __launch_bounds__(256) void bert_embed_kernel(
    const int*    __restrict__ seq,       // [B,L]
    const float4* __restrict__ tok_tab,   // [VOCAB, 32] (float4 view)
    const float4* __restrict__ gen_tab,   // [21, 32]
    const float4* __restrict__ pos_tab,   // [200, 32]
    const int*    __restrict__ tgid,      // [VOCAB, 8]
    const int*    __restrict__ gcnt,      // [VOCAB]
    float4*       __restrict__ out)       // [B,L,32]
{
    const int tid   = threadIdx.x;
    const int group = tid >> 5;          // token slot within block (0..7)
    const int lane  = tid & 31;          // float4 index within row (0..31)

    const int idx0 = blockIdx.x * 8 + group;   // 0..HALF-1
    const int idx1 = idx0 + HALF;              // HALF..NTOK-1
    if (idx0 >= HALF) return;

    // ---- level 0: both seq loads + both pos loads (independent) ----
    const int t0 = seq[idx0];
    const int t1 = seq[idx1];
    const float4 p0 = pos_tab[(idx0 % L_SZ) * F4_PER_ROW + lane];
    const float4 p1 = pos_tab[(idx1 % L_SZ) * F4_PER_ROW + lane];

    // ---- level 1: token rows, counts, genre-id vectors for both chains ----
    const float4 tokv0 = tok_tab[(long)t0 * F4_PER_ROW + lane];
    const float4 tokv1 = tok_tab[(long)t1 * F4_PER_ROW + lane];
    const int cnt0 = gcnt[t0];
    const int cnt1 = gcnt[t1];
    const int4* g40 = (const int4*)(tgid + (long)t0 * MAX_G);
    const int4* g41 = (const int4*)(tgid + (long)t1 * MAX_G);
    const int4 ga0 = g40[0], gb0 = g40[1];
    const int4 ga1 = g41[0], gb1 = g41[1];
    const int gid0[MAX_G] = { ga0.x, ga0.y, ga0.z, ga0.w, gb0.x, gb0.y, gb0.z, gb0.w };
    const int gid1[MAX_G] = { ga1.x, ga1.y, ga1.z, ga1.w, gb1.x, gb1.y, gb1.z, gb1.w };

    // ---- level 2: all 16 genre-row loads issued independently (L1-hot) ----
    float4 r0[MAX_G], r1[MAX_G];
    #pragma unroll
    for (int i = 0; i < MAX_G; ++i) r0[i] = gen_tab[gid0[i] * F4_PER_ROW + lane];
    #pragma unroll
    for (int i = 0; i < MAX_G; ++i) r1[i] = gen_tab[gid1[i] * F4_PER_ROW + lane];

    // ---- compute + store chain 0 ----
    {
        const float inv = 1.0f / (float)cnt0;
        nativef4 acc;
        acc.x = tokv0.x + p0.x; acc.y = tokv0.y + p0.y;
        acc.z = tokv0.z + p0.z; acc.w = tokv0.w + p0.w;
        #pragma unroll
        for (int i = 0; i < MAX_G; ++i) {
            const float w = (i < cnt0) ? inv : 0.0f;
            acc.x = fmaf(w, r0[i].x, acc.x);
            acc.y = fmaf(w, r0[i].y, acc.y);
            acc.z = fmaf(w, r0[i].z, acc.z);
            acc.w = fmaf(w, r0[i].w, acc.w);
        }
        __builtin_nontemporal_store(acc,
            (nativef4*)&out[(long)idx0 * F4_PER_ROW + lane]);
    }
    // ---- compute + store chain 1 ----
    {
        const float inv = 1.0f / (float)cnt1;
        nativef4 acc;
        acc.x = tokv1.x + p1.x; acc.y = tokv1.y + p1.y;
        acc.z = tokv1.z + p1.z; acc.w = tokv1.w + p1.w;
        #pragma unroll
        for (int i = 0; i < MAX_G; ++i) {
            const float w = (i < cnt1) ? inv : 0.0f;
            acc.x = fmaf(w, r1[i].x, acc.x);
            acc.y = fmaf(w, r1[i].y, acc.y);
            acc.z = fmaf(w, r1[i].z, acc.z);
            acc.w = fmaf(w, r1[i].w, acc.w);
        }
        __builtin_nontemporal_store(acc,
            (nativef4*)&out[(long)idx1 * F4_PER_ROW + lane]);
    }
}

extern "C" void kernel_launch(void* const* d_in, const int* in_sizes, int n_in,
                              void* d_out, int out_size, void* d_ws, size_t ws_size,
                              hipStream_t stream) {
    const int*    seq     = (const int*)   d_in[0];  // sequence (256,200) int32
    const float4* tok_tab = (const float4*)d_in[1];  // token_table (100000,128) f32
    const float4* gen_tab = (const float4*)d_in[2];  // genre_table (21,128) f32
    const float4* pos_tab = (const float4*)d_in[3];  // pos_table (200,128) f32
    const int*    tgid    = (const int*)   d_in[4];  // token_genre_ids (100000,8)
    const int*    gcnt    = (const int*)   d_in[5];  // genre_counts (100000,)
    float4*       out     = (float4*)      d_out;    // (256,200,128) f32

    const int blocks = HALF / 8;  // 3200
    bert_embed_kernel<<<blocks, 256, 0, stream>>>(seq, tok_tab, gen_tab,
                                                  pos_tab, tgid, gcnt, out);
}